// Round 1
// baseline (13471.783 us; speedup 1.0000x reference)
//
#include <hip/hip_runtime.h>
#include <hip/hip_bf16.h>

typedef short s8v __attribute__((ext_vector_type(8)));
typedef float f4v __attribute__((ext_vector_type(4)));

#define NBLK 64
#define TPB 256

constexpr int BB = 32, TT = 512, DD = 512, HH = 1024;
constexpr int KK = DD + HH;          // 1536
constexpr int PK = KK + 8;           // 1544 = 8*193  (padded LDS K-stride)
constexpr int PK8 = PK / 8;          // 193
constexpr int K8 = KK / 8;           // 192

// ---- workspace layout (bytes) ----
constexpr size_t OFF_WGT = 0;                                   // [2048][1536] bf16
constexpr size_t SZ_WGT  = (size_t)2 * HH * KK * 2;             // 6,291,456
constexpr size_t OFF_WCT = OFF_WGT + SZ_WGT;                    // [1024][1536] bf16
constexpr size_t SZ_WCT  = (size_t)HH * KK * 2;                 // 3,145,728
constexpr size_t OFF_XBF = OFF_WCT + SZ_WCT;                    // [32][512][512] bf16
constexpr size_t SZ_XBF  = (size_t)BB * TT * DD * 2;            // 16,777,216
constexpr size_t OFF_HBF = OFF_XBF + SZ_XBF;                    // [32][1024] bf16
constexpr size_t SZ_HBF  = (size_t)BB * HH * 2;
constexpr size_t OFF_RHB = OFF_HBF + SZ_HBF;                    // [32][1024] bf16
constexpr size_t SZ_RHB  = (size_t)BB * HH * 2;
constexpr size_t OFF_UF  = OFF_RHB + SZ_RHB;                    // [32][1024] f32
constexpr size_t SZ_UF   = (size_t)BB * HH * 4;
constexpr size_t OFF_FLG = OFF_UF + SZ_UF;                      // 2*512 counters, 64B apart
constexpr size_t SZ_FLG  = (size_t)2 * TT * 16 * 4;             // 65,536

// ---------------------------------------------------------------------------
// One-time: transpose fp32 [KK][N] -> bf16 [N][KK]
__global__ void wtr_kernel(const float* __restrict__ in, unsigned short* __restrict__ out, int N) {
    __shared__ float tl[32][33];
    int tx = threadIdx.x & 31, ty = threadIdx.x >> 5;
    int n0 = blockIdx.x * 32, k0 = blockIdx.y * 32;
#pragma unroll
    for (int r = ty; r < 32; r += 8) tl[r][tx] = in[(size_t)(k0 + r) * N + n0 + tx];
    __syncthreads();
#pragma unroll
    for (int r = ty; r < 32; r += 8) {
        __hip_bfloat16 h = __float2bfloat16(tl[tx][r]);
        out[(size_t)(n0 + r) * KK + k0 + tx] = *reinterpret_cast<unsigned short*>(&h);
    }
}

// One-time: X fp32 -> bf16
__global__ void xconv_kernel(const float* __restrict__ X, unsigned short* __restrict__ Xbf) {
    size_t i = ((size_t)blockIdx.x * TPB + threadIdx.x) * 4;
    float4 v = *reinterpret_cast<const float4*>(X + i);
    __hip_bfloat16 h0 = __float2bfloat16(v.x), h1 = __float2bfloat16(v.y);
    __hip_bfloat16 h2 = __float2bfloat16(v.z), h3 = __float2bfloat16(v.w);
    ushort4 o;
    o.x = *(unsigned short*)&h0; o.y = *(unsigned short*)&h1;
    o.z = *(unsigned short*)&h2; o.w = *(unsigned short*)&h3;
    *reinterpret_cast<ushort4*>(Xbf + i) = o;
}

// ---------------------------------------------------------------------------
__device__ __forceinline__ void block_arrive(int* f) {
    __syncthreads();                       // drains vmcnt: all block stores at L2
    if (threadIdx.x == 0) {
        __threadfence();                   // agent release: L2 writeback to coherent point
        __hip_atomic_fetch_add(f, 1, __ATOMIC_RELAXED, __HIP_MEMORY_SCOPE_AGENT);
    }
}
__device__ __forceinline__ void wait_count(int* f, int target) {
    while (__hip_atomic_load(f, __ATOMIC_RELAXED, __HIP_MEMORY_SCOPE_AGENT) < target) {
        __builtin_amdgcn_s_sleep(1);
    }
    __threadfence();                       // agent acquire: invalidate stale L1/L2
}

// ---------------------------------------------------------------------------
// Persistent recurrent kernel. 64 blocks x 256 threads, 1 block/CU (LDS-bound).
// Block b owns gate cols [b*32, b*32+32) and candidate cols [b*16, b*16+16).
__global__ __launch_bounds__(TPB, 1) void gru_kernel(
    const unsigned short* __restrict__ Xbf,
    const unsigned short* __restrict__ WgT,
    const unsigned short* __restrict__ WcT,
    const float* __restrict__ bg,
    const float* __restrict__ bc,
    float* __restrict__ out,
    unsigned short* __restrict__ hbf,
    unsigned short* __restrict__ rhbf,
    float* __restrict__ uf,
    int* __restrict__ flags)
{
    __shared__ unsigned short sWg[32 * PK];   // 98,816 B
    __shared__ unsigned short sWc[16 * PK];   // 49,408 B
    __shared__ float sRed[2][16][16];         //  2,048 B  (total 150,272 < 160K)

    const int b    = blockIdx.x;
    const int tid  = threadIdx.x;
    const int wid  = tid >> 6;
    const int lane = tid & 63;
    const int l15  = lane & 15;
    const int kq   = lane >> 4;

    // ---- stage weight slices into LDS (once) ----
    {
        const s8v* src = (const s8v*)(WgT + (size_t)b * 32 * KK);
        s8v* dst = (s8v*)sWg;
        for (int idx = tid; idx < 32 * K8; idx += TPB) {
            int c = idx / K8, k8 = idx % K8;
            dst[c * PK8 + k8] = src[c * K8 + k8];
        }
        const s8v* src2 = (const s8v*)(WcT + (size_t)b * 16 * KK);
        s8v* dst2 = (s8v*)sWc;
        for (int idx = tid; idx < 16 * K8; idx += TPB) {
            int c = idx / K8, k8 = idx % K8;
            dst2[c * PK8 + k8] = src2[c * K8 + k8];
        }
    }

    int* flagsA = flags;
    int* flagsB = flags + TT * 16;

    const int   roff   = (wid >> 1) * 16;          // batch-row tile offset
    const int   colA_l = ((wid & 1) << 4) + l15;   // local gate col 0..31
    const int   gcol   = b * 32 + colA_l;          // global gate col 0..2047
    const float bgv    = bg[gcol];
    const int   ccol   = b * 16 + l15;             // global cand col 0..1023
    const float bcv    = bc[ccol];
    const bool  isR    = (b < 32);                 // this block's gate cols are r-cols
    const int   arow   = roff + l15;               // A-fragment batch row

    const s8v* sWg8 = (const s8v*)sWg;
    const s8v* sWc8 = (const s8v*)sWc;
    const s8v* bwgx = sWg8 + colA_l * PK8 + kq;    // gate weights, x part
    const s8v* bwgh = bwgx + DD / 8;               // gate weights, h part
    const s8v* bwcx = sWc8 + l15 * PK8 + kq;       // cand weights, x part
    const s8v* bwch = bwcx + DD / 8;               // cand weights, rh part

    __syncthreads();

#pragma unroll 1
    for (int t = 0; t < TT; ++t) {
        if (t > 0) wait_count(&flagsB[(t - 1) * 16], NBLK);   // h_{t-1} ready

        // =================== Phase A: gates ===================
        const s8v* xap = (const s8v*)(Xbf + (size_t)arow * (TT * DD) + (size_t)t * DD) + kq;
        const s8v* hap = (const s8v*)(hbf + (size_t)arow * HH) + kq;

        float hold[4];
        if (isR) {
#pragma unroll
            for (int i = 0; i < 4; i++) {
                int row = roff + kq * 4 + i;
                hold[i] = (t > 0) ? out[(size_t)row * (TT * HH) + (size_t)(t - 1) * HH + gcol] : 0.f;
            }
        }

        f4v acc = {0.f, 0.f, 0.f, 0.f};
#pragma unroll
        for (int kx = 0; kx < DD / 32; ++kx)
            acc = __builtin_amdgcn_mfma_f32_16x16x32_bf16(xap[kx * 4], bwgx[kx * 4], acc, 0, 0, 0);
        if (t > 0) {
#pragma unroll
            for (int kh = 0; kh < HH / 32; ++kh)
                acc = __builtin_amdgcn_mfma_f32_16x16x32_bf16(hap[kh * 4], bwgh[kh * 4], acc, 0, 0, 0);
        }

#pragma unroll
        for (int i = 0; i < 4; i++) {
            int row = roff + kq * 4 + i;
            float z = acc[i] + bgv;
            float g = 1.f / (1.f + __expf(-z));
            if (isR) {
                __hip_bfloat16 hb = __float2bfloat16(g * hold[i]);
                rhbf[row * HH + gcol] = *(unsigned short*)&hb;
            } else {
                uf[row * HH + (gcol - HH)] = g;
            }
        }
        block_arrive(&flagsA[t * 16]);
        wait_count(&flagsA[t * 16], NBLK);

        // =================== Phase B: candidate + h update ===================
        const s8v* rap = (const s8v*)(rhbf + (size_t)arow * HH) + kq;
        const int khalf = wid & 1;

        float uv[4], hov[4];
        if (khalf == 0) {
#pragma unroll
            for (int i = 0; i < 4; i++) {
                int row = roff + kq * 4 + i;
                uv[i]  = uf[row * HH + ccol];
                hov[i] = (t > 0) ? out[(size_t)row * (TT * HH) + (size_t)(t - 1) * HH + ccol] : 0.f;
            }
        }

        f4v acc2 = {0.f, 0.f, 0.f, 0.f};
        if (khalf == 0) {
#pragma unroll
            for (int kx = 0; kx < DD / 32; ++kx)
                acc2 = __builtin_amdgcn_mfma_f32_16x16x32_bf16(xap[kx * 4], bwcx[kx * 4], acc2, 0, 0, 0);
#pragma unroll
            for (int kh = 0; kh < 8; ++kh)
                acc2 = __builtin_amdgcn_mfma_f32_16x16x32_bf16(rap[kh * 4], bwch[kh * 4], acc2, 0, 0, 0);
        } else {
#pragma unroll
            for (int kh = 8; kh < HH / 32; ++kh)
                acc2 = __builtin_amdgcn_mfma_f32_16x16x32_bf16(rap[kh * 4], bwch[kh * 4], acc2, 0, 0, 0);
        }

        if (khalf == 1) {
#pragma unroll
            for (int i = 0; i < 4; i++) sRed[wid >> 1][kq * 4 + i][l15] = acc2[i];
        }
        __syncthreads();
        if (khalf == 0) {
#pragma unroll
            for (int i = 0; i < 4; i++) {
                int row = roff + kq * 4 + i;
                float z = acc2[i] + sRed[wid >> 1][kq * 4 + i][l15] + bcv;
                float e = __expf(2.f * z);
                float cv = 1.f - 2.f / (e + 1.f);
                float hn = uv[i] * hov[i] + (1.f - uv[i]) * cv;
                out[(size_t)row * (TT * HH) + (size_t)t * HH + ccol] = hn;
                __hip_bfloat16 hb = __float2bfloat16(hn);
                hbf[row * HH + ccol] = *(unsigned short*)&hb;
            }
        }
        block_arrive(&flagsB[t * 16]);
    }
}

// ---------------------------------------------------------------------------
extern "C" void kernel_launch(void* const* d_in, const int* in_sizes, int n_in,
                              void* d_out, int out_size, void* d_ws, size_t ws_size,
                              hipStream_t stream) {
    const float* X  = (const float*)d_in[0];
    const float* gk = (const float*)d_in[1];
    const float* gb = (const float*)d_in[2];
    const float* ck = (const float*)d_in[3];
    const float* cb = (const float*)d_in[4];
    float* out = (float*)d_out;
    char* ws = (char*)d_ws;
    if (ws_size < OFF_FLG + SZ_FLG) return;  // workspace too small — bail

    unsigned short* WgT  = (unsigned short*)(ws + OFF_WGT);
    unsigned short* WcT  = (unsigned short*)(ws + OFF_WCT);
    unsigned short* Xbf  = (unsigned short*)(ws + OFF_XBF);
    unsigned short* hbf  = (unsigned short*)(ws + OFF_HBF);
    unsigned short* rhbf = (unsigned short*)(ws + OFF_RHB);
    float*          uf   = (float*)(ws + OFF_UF);
    int*            flags= (int*)(ws + OFF_FLG);

    hipMemsetAsync(flags, 0, SZ_FLG, stream);

    dim3 tb(TPB);
    wtr_kernel<<<dim3(2 * HH / 32, KK / 32), tb, 0, stream>>>(gk, WgT, 2 * HH);
    wtr_kernel<<<dim3(HH / 32, KK / 32), tb, 0, stream>>>(ck, WcT, HH);
    xconv_kernel<<<(BB * TT * DD) / (TPB * 4), tb, 0, stream>>>(X, Xbf);

    gru_kernel<<<NBLK, tb, 0, stream>>>(Xbf, WgT, WcT, gb, cb, out,
                                        hbf, rhbf, uf, flags);
}

// Round 2
// 9356.474 us; speedup vs baseline: 1.4398x; 1.4398x over previous
//
#include <hip/hip_runtime.h>
#include <hip/hip_bf16.h>

typedef short s8v __attribute__((ext_vector_type(8)));
typedef float f4v __attribute__((ext_vector_type(4)));

#define NBLK 64
#define TPB 256

constexpr int BB = 32, TT = 512, DD = 512, HH = 1024;
constexpr int KK = DD + HH;          // 1536
constexpr int PK = KK + 8;           // 1544 (padded LDS K-stride)
constexpr int PK8 = PK / 8;          // 193
constexpr int K8 = KK / 8;           // 192

// ---- workspace layout (bytes) ----
constexpr size_t OFF_WGT = 0;                                   // [2048][1536] bf16
constexpr size_t SZ_WGT  = (size_t)2 * HH * KK * 2;
constexpr size_t OFF_WCT = OFF_WGT + SZ_WGT;                    // [1024][1536] bf16
constexpr size_t SZ_WCT  = (size_t)HH * KK * 2;
constexpr size_t OFF_XBF = OFF_WCT + SZ_WCT;                    // [32][512][512] bf16
constexpr size_t SZ_XBF  = (size_t)BB * TT * DD * 2;
constexpr size_t OFF_HBF = OFF_XBF + SZ_XBF;                    // [32][1024] bf16
constexpr size_t SZ_HBF  = (size_t)BB * HH * 2;
constexpr size_t OFF_RHB = OFF_HBF + SZ_HBF;                    // [32][1024] bf16
constexpr size_t SZ_RHB  = (size_t)BB * HH * 2;
constexpr size_t OFF_UF  = OFF_RHB + SZ_RHB;                    // [32][1024] f32
constexpr size_t SZ_UF   = (size_t)BB * HH * 4;
constexpr size_t OFF_HF  = OFF_UF + SZ_UF;                      // [32][1024] f32 (h state)
constexpr size_t SZ_HF   = (size_t)BB * HH * 4;
constexpr size_t OFF_FLG = OFF_HF + SZ_HF;                      // 64 ints (per-block gen flags)
constexpr size_t SZ_FLG  = (size_t)NBLK * 4;

// ---------------------------------------------------------------------------
// One-time: transpose fp32 [KK][N] -> bf16 [N][KK]
__global__ void wtr_kernel(const float* __restrict__ in, unsigned short* __restrict__ out, int N) {
    __shared__ float tl[32][33];
    int tx = threadIdx.x & 31, ty = threadIdx.x >> 5;
    int n0 = blockIdx.x * 32, k0 = blockIdx.y * 32;
#pragma unroll
    for (int r = ty; r < 32; r += 8) tl[r][tx] = in[(size_t)(k0 + r) * N + n0 + tx];
    __syncthreads();
#pragma unroll
    for (int r = ty; r < 32; r += 8) {
        __hip_bfloat16 h = __float2bfloat16(tl[tx][r]);
        out[(size_t)(n0 + r) * KK + k0 + tx] = *reinterpret_cast<unsigned short*>(&h);
    }
}

// One-time: X fp32 -> bf16
__global__ void xconv_kernel(const float* __restrict__ X, unsigned short* __restrict__ Xbf) {
    size_t i = ((size_t)blockIdx.x * TPB + threadIdx.x) * 4;
    float4 v = *reinterpret_cast<const float4*>(X + i);
    __hip_bfloat16 h0 = __float2bfloat16(v.x), h1 = __float2bfloat16(v.y);
    __hip_bfloat16 h2 = __float2bfloat16(v.z), h3 = __float2bfloat16(v.w);
    ushort4 o;
    o.x = *(unsigned short*)&h0; o.y = *(unsigned short*)&h1;
    o.z = *(unsigned short*)&h2; o.w = *(unsigned short*)&h3;
    *reinterpret_cast<ushort4*>(Xbf + i) = o;
}

// ---------------------------------------------------------------------------
// Flag-array barrier: per-block slot, monotonic generation numbers.
// arrive: block-local barrier drains stores to L2; ONE thread does the agent
//         release fence (buffer_wbl2) then publishes its generation.
// wait:   wave 0 lane-parallel-polls all 64 slots (bypassing caches via
//         agent-scope atomic loads), then one acquire fence (buffer_inv)
//         per wave invalidates stale L1/L2 lines.
__device__ __forceinline__ void gru_arrive(int* __restrict__ flags, int slot, int gen) {
    __syncthreads();
    if (threadIdx.x == 0) {
        __builtin_amdgcn_fence(__ATOMIC_RELEASE, "agent");
        __hip_atomic_store(&flags[slot], gen, __ATOMIC_RELAXED, __HIP_MEMORY_SCOPE_AGENT);
    }
}
__device__ __forceinline__ void gru_wait(int* __restrict__ flags, int gen) {
    if (threadIdx.x < NBLK) {
        while (__hip_atomic_load(&flags[threadIdx.x], __ATOMIC_RELAXED,
                                 __HIP_MEMORY_SCOPE_AGENT) < gen) {
            __builtin_amdgcn_s_sleep(1);
        }
    }
    __syncthreads();
    __builtin_amdgcn_fence(__ATOMIC_ACQUIRE, "agent");
}

// ---------------------------------------------------------------------------
// Persistent recurrent kernel. 64 blocks x 256 threads, 1 block/CU (LDS-bound).
// Block b owns gate cols [b*32, b*32+32) and candidate cols [b*16, b*16+16).
__global__ __launch_bounds__(TPB, 1) void gru_kernel(
    const unsigned short* __restrict__ Xbf,
    const unsigned short* __restrict__ WgT,
    const unsigned short* __restrict__ WcT,
    const float* __restrict__ bg,
    const float* __restrict__ bc,
    float* __restrict__ out,
    unsigned short* __restrict__ hbf,
    unsigned short* __restrict__ rhbf,
    float* __restrict__ uf,
    float* __restrict__ hf32,
    int* __restrict__ flags)
{
    __shared__ unsigned short sWg[32 * PK];   // 98,816 B
    __shared__ unsigned short sWc[16 * PK];   // 49,408 B
    __shared__ float sRed[2][16][16];         //  2,048 B

    const int b    = blockIdx.x;
    const int tid  = threadIdx.x;
    const int wid  = tid >> 6;
    const int lane = tid & 63;
    const int l15  = lane & 15;
    const int kq   = lane >> 4;

    // ---- stage weight slices into LDS (once) ----
    {
        const s8v* src = (const s8v*)(WgT + (size_t)b * 32 * KK);
        s8v* dst = (s8v*)sWg;
        for (int idx = tid; idx < 32 * K8; idx += TPB) {
            int c = idx / K8, k8 = idx % K8;
            dst[c * PK8 + k8] = src[c * K8 + k8];
        }
        const s8v* src2 = (const s8v*)(WcT + (size_t)b * 16 * KK);
        s8v* dst2 = (s8v*)sWc;
        for (int idx = tid; idx < 16 * K8; idx += TPB) {
            int c = idx / K8, k8 = idx % K8;
            dst2[c * PK8 + k8] = src2[c * K8 + k8];
        }
    }

    const int   roff   = (wid >> 1) * 16;          // batch-row tile offset
    const int   khalf  = wid & 1;
    const int   colA_l = (khalf << 4) + l15;       // local gate col 0..31
    const int   gcol   = b * 32 + colA_l;          // global gate col 0..2047
    const float bgv    = bg[gcol];
    const int   ccol   = b * 16 + l15;             // global cand col 0..1023
    const float bcv    = bc[ccol];
    const bool  isR    = (b < 32);                 // this block's gate cols are r-cols
    const int   arow   = roff + l15;               // A-fragment batch row

    const s8v* sWg8 = (const s8v*)sWg;
    const s8v* sWc8 = (const s8v*)sWc;
    const s8v* bwgx = sWg8 + colA_l * PK8 + kq;    // gate weights, x part
    const s8v* bwgh = bwgx + DD / 8;               // gate weights, h part
    const s8v* bwcx = sWc8 + l15 * PK8 + kq;       // cand weights, x part
    const s8v* bwch = bwcx + DD / 8;               // cand weights, rh part

    __syncthreads();

#pragma unroll 1
    for (int t = 0; t < TT; ++t) {
        const s8v* xap = (const s8v*)(Xbf + (size_t)arow * (TT * DD) + (size_t)t * DD) + kq;

        // ---- Phase A: gate X-part (independent of h_{t-1}) BEFORE the wait ----
        f4v a0 = {0.f, 0.f, 0.f, 0.f}, a1 = {0.f, 0.f, 0.f, 0.f};
#pragma unroll
        for (int kx = 0; kx < DD / 32; kx += 2) {
            a0 = __builtin_amdgcn_mfma_f32_16x16x32_bf16(xap[kx * 4],       bwgx[kx * 4],       a0, 0, 0, 0);
            a1 = __builtin_amdgcn_mfma_f32_16x16x32_bf16(xap[(kx + 1) * 4], bwgx[(kx + 1) * 4], a1, 0, 0, 0);
        }

        float hold[4] = {0.f, 0.f, 0.f, 0.f};
        if (t > 0) {
            gru_wait(flags, 2 * t);                // h_{t-1} published by all blocks
            if (isR) {
#pragma unroll
                for (int i = 0; i < 4; i++)
                    hold[i] = hf32[(roff + kq * 4 + i) * HH + gcol];
            }
            const s8v* hap = (const s8v*)(hbf + (size_t)arow * HH) + kq;
#pragma unroll
            for (int kh = 0; kh < HH / 32; kh += 2) {
                a0 = __builtin_amdgcn_mfma_f32_16x16x32_bf16(hap[kh * 4],       bwgh[kh * 4],       a0, 0, 0, 0);
                a1 = __builtin_amdgcn_mfma_f32_16x16x32_bf16(hap[(kh + 1) * 4], bwgh[(kh + 1) * 4], a1, 0, 0, 0);
            }
        }

#pragma unroll
        for (int i = 0; i < 4; i++) {
            int row = roff + kq * 4 + i;
            float z = a0[i] + a1[i] + bgv;
            float g = 1.f / (1.f + __expf(-z));
            if (isR) {
                __hip_bfloat16 hb = __float2bfloat16(g * hold[i]);
                rhbf[row * HH + gcol] = *(unsigned short*)&hb;
            } else {
                uf[row * HH + (gcol - HH)] = g;
            }
        }
        gru_arrive(flags, b, 2 * t + 1);

        // ---- Phase B: candidate X-part (independent of rh) BEFORE the wait ----
        f4v c0 = {0.f, 0.f, 0.f, 0.f}, c1 = {0.f, 0.f, 0.f, 0.f};
        if (khalf == 0) {
#pragma unroll
            for (int kx = 0; kx < DD / 32; kx += 2) {
                c0 = __builtin_amdgcn_mfma_f32_16x16x32_bf16(xap[kx * 4],       bwcx[kx * 4],       c0, 0, 0, 0);
                c1 = __builtin_amdgcn_mfma_f32_16x16x32_bf16(xap[(kx + 1) * 4], bwcx[(kx + 1) * 4], c1, 0, 0, 0);
            }
        }
        gru_wait(flags, 2 * t + 1);                // rh, u published by all blocks

        float uv[4], hov[4];
        if (khalf == 0) {
#pragma unroll
            for (int i = 0; i < 4; i++) {
                int row = roff + kq * 4 + i;
                uv[i]  = uf[row * HH + ccol];
                hov[i] = (t > 0) ? hf32[row * HH + ccol] : 0.f;
            }
        }

        const s8v* rap = (const s8v*)(rhbf + (size_t)arow * HH) + kq;
        if (khalf == 0) {
#pragma unroll
            for (int kh = 0; kh < 8; kh += 2) {
                c0 = __builtin_amdgcn_mfma_f32_16x16x32_bf16(rap[kh * 4],       bwch[kh * 4],       c0, 0, 0, 0);
                c1 = __builtin_amdgcn_mfma_f32_16x16x32_bf16(rap[(kh + 1) * 4], bwch[(kh + 1) * 4], c1, 0, 0, 0);
            }
        } else {
#pragma unroll
            for (int kh = 8; kh < HH / 32; kh += 2) {
                c0 = __builtin_amdgcn_mfma_f32_16x16x32_bf16(rap[kh * 4],       bwch[kh * 4],       c0, 0, 0, 0);
                c1 = __builtin_amdgcn_mfma_f32_16x16x32_bf16(rap[(kh + 1) * 4], bwch[(kh + 1) * 4], c1, 0, 0, 0);
            }
        }
        f4v c2 = c0 + c1;

        if (khalf == 1) {
#pragma unroll
            for (int i = 0; i < 4; i++) sRed[wid >> 1][kq * 4 + i][l15] = c2[i];
        }
        __syncthreads();
        if (khalf == 0) {
#pragma unroll
            for (int i = 0; i < 4; i++) {
                int row = roff + kq * 4 + i;
                float z = c2[i] + sRed[wid >> 1][kq * 4 + i][l15] + bcv;
                float e = __expf(2.f * z);
                float cv = 1.f - 2.f / (e + 1.f);
                float hn = uv[i] * hov[i] + (1.f - uv[i]) * cv;
                out[(size_t)row * (TT * HH) + (size_t)t * HH + ccol] = hn;
                hf32[row * HH + ccol] = hn;
                __hip_bfloat16 hb = __float2bfloat16(hn);
                hbf[row * HH + ccol] = *(unsigned short*)&hb;
            }
        }
        gru_arrive(flags, b, 2 * t + 2);
    }
}

// ---------------------------------------------------------------------------
extern "C" void kernel_launch(void* const* d_in, const int* in_sizes, int n_in,
                              void* d_out, int out_size, void* d_ws, size_t ws_size,
                              hipStream_t stream) {
    const float* X  = (const float*)d_in[0];
    const float* gk = (const float*)d_in[1];
    const float* gb = (const float*)d_in[2];
    const float* ck = (const float*)d_in[3];
    const float* cb = (const float*)d_in[4];
    float* out = (float*)d_out;
    char* ws = (char*)d_ws;
    if (ws_size < OFF_FLG + SZ_FLG) return;  // workspace too small — bail

    unsigned short* WgT  = (unsigned short*)(ws + OFF_WGT);
    unsigned short* WcT  = (unsigned short*)(ws + OFF_WCT);
    unsigned short* Xbf  = (unsigned short*)(ws + OFF_XBF);
    unsigned short* hbf  = (unsigned short*)(ws + OFF_HBF);
    unsigned short* rhbf = (unsigned short*)(ws + OFF_RHB);
    float*          uf   = (float*)(ws + OFF_UF);
    float*          hf32 = (float*)(ws + OFF_HF);
    int*            flags= (int*)(ws + OFF_FLG);

    hipMemsetAsync(flags, 0, SZ_FLG, stream);

    dim3 tb(TPB);
    wtr_kernel<<<dim3(2 * HH / 32, KK / 32), tb, 0, stream>>>(gk, WgT, 2 * HH);
    wtr_kernel<<<dim3(HH / 32, KK / 32), tb, 0, stream>>>(ck, WcT, HH);
    xconv_kernel<<<(BB * TT * DD) / (TPB * 4), tb, 0, stream>>>(X, Xbf);

    gru_kernel<<<NBLK, tb, 0, stream>>>(Xbf, WgT, WcT, gb, cb, out,
                                        hbf, rhbf, uf, hf32, flags);
}

// Round 3
// 8418.867 us; speedup vs baseline: 1.6002x; 1.1114x over previous
//
#include <hip/hip_runtime.h>
#include <hip/hip_bf16.h>

typedef short s8v __attribute__((ext_vector_type(8)));
typedef float f4v __attribute__((ext_vector_type(4)));
typedef unsigned long long u64;

#define NBLK 64
#define TPB 256

constexpr int BB = 32, TT = 512, DD = 512, HH = 1024;
constexpr int KK = DD + HH;          // 1536
constexpr int PK = KK + 8;           // padded LDS K-stride
constexpr int PK8 = PK / 8;
constexpr int K8 = KK / 8;
constexpr int NCH_X = DD / 32;       // 16 k-chunks in x-part
constexpr int NCH_H = HH / 32;       // 32 k-chunks in h-part

// ---- workspace layout (bytes) ----
constexpr size_t OFF_WGT = 0;                                   // [2048][1536] bf16
constexpr size_t SZ_WGT  = (size_t)2 * HH * KK * 2;
constexpr size_t OFF_WCT = OFF_WGT + SZ_WGT;                    // [1024][1536] bf16
constexpr size_t SZ_WCT  = (size_t)HH * KK * 2;
constexpr size_t OFF_XBF = OFF_WCT + SZ_WCT;                    // [32][512][512] bf16
constexpr size_t SZ_XBF  = (size_t)BB * TT * DD * 2;
constexpr size_t OFF_HBF = OFF_XBF + SZ_XBF;                    // [32][1024] bf16
constexpr size_t SZ_HBF  = (size_t)BB * HH * 2;
constexpr size_t OFF_RHB = OFF_HBF + SZ_HBF;                    // [32][1024] bf16
constexpr size_t SZ_RHB  = (size_t)BB * HH * 2;
constexpr size_t OFF_FLG = OFF_RHB + SZ_RHB;                    // flagsA[64] + flagsB[64]
constexpr size_t SZ_FLG  = (size_t)2 * NBLK * 4;

// ---------------------------------------------------------------------------
__global__ void wtr_kernel(const float* __restrict__ in, unsigned short* __restrict__ out, int N) {
    __shared__ float tl[32][33];
    int tx = threadIdx.x & 31, ty = threadIdx.x >> 5;
    int n0 = blockIdx.x * 32, k0 = blockIdx.y * 32;
#pragma unroll
    for (int r = ty; r < 32; r += 8) tl[r][tx] = in[(size_t)(k0 + r) * N + n0 + tx];
    __syncthreads();
#pragma unroll
    for (int r = ty; r < 32; r += 8) {
        __hip_bfloat16 h = __float2bfloat16(tl[tx][r]);
        out[(size_t)(n0 + r) * KK + k0 + tx] = *reinterpret_cast<unsigned short*>(&h);
    }
}

__global__ void xconv_kernel(const float* __restrict__ X, unsigned short* __restrict__ Xbf) {
    size_t i = ((size_t)blockIdx.x * TPB + threadIdx.x) * 4;
    float4 v = *reinterpret_cast<const float4*>(X + i);
    __hip_bfloat16 h0 = __float2bfloat16(v.x), h1 = __float2bfloat16(v.y);
    __hip_bfloat16 h2 = __float2bfloat16(v.z), h3 = __float2bfloat16(v.w);
    ushort4 o;
    o.x = *(unsigned short*)&h0; o.y = *(unsigned short*)&h1;
    o.z = *(unsigned short*)&h2; o.w = *(unsigned short*)&h3;
    *reinterpret_cast<ushort4*>(Xbf + i) = o;
}

// ---------------------------------------------------------------------------
// Coherent (agent-scope, L1/L2-bypassing) access helpers. No fences anywhere:
// data itself travels through the IF$ coherence point.
__device__ __forceinline__ s8v cload_chunk(const u64* p) {
    union { u64 q[2]; s8v v; } u;
    u.q[0] = __hip_atomic_load(p,     __ATOMIC_RELAXED, __HIP_MEMORY_SCOPE_AGENT);
    u.q[1] = __hip_atomic_load(p + 1, __ATOMIC_RELAXED, __HIP_MEMORY_SCOPE_AGENT);
    return u.v;
}
__device__ __forceinline__ void cstore_short(unsigned short* p, unsigned short v) {
    unsigned int vv = v;
    asm volatile("global_store_short %0, %1, off sc0 sc1" :: "v"(p), "v"(vv) : "memory");
}
__device__ __forceinline__ void wait_flags(int* f, int gen) {
    if (threadIdx.x < NBLK) {
        while (__hip_atomic_load(&f[threadIdx.x], __ATOMIC_RELAXED,
                                 __HIP_MEMORY_SCOPE_AGENT) < gen) {
            __builtin_amdgcn_s_sleep(1);
        }
    }
    __syncthreads();
    asm volatile("" ::: "memory");
}

#define MFMA(A, B, C) __builtin_amdgcn_mfma_f32_16x16x32_bf16((A), (B), (C), 0, 0, 0)

// ---------------------------------------------------------------------------
// Persistent kernel, 64 blocks x 256 threads, 1 block/CU.
// Block b owns r-cols, u-cols and candidate-cols [b*16, b*16+16):
//   - u stays block-local (LDS), h_prev for r*h and the h-update lives in
//     registers of the SAME thread across all timesteps.
// Waves: wid = rt*2 + khalf. rt = batch-row tile (rows rt*16..+16).
//   Phase A: khalf0 computes r-cols, khalf1 computes u-cols.
//   Phase B: khalf splits the K dimension of the candidate GEMM.
__global__ __launch_bounds__(TPB, 1) void gru_kernel(
    const unsigned short* __restrict__ Xbf,
    const unsigned short* __restrict__ WgT,
    const unsigned short* __restrict__ WcT,
    const float* __restrict__ bg,
    const float* __restrict__ bc,
    float* __restrict__ out,
    unsigned short* __restrict__ hbf,
    unsigned short* __restrict__ rhbf,
    int* __restrict__ flagsA,
    int* __restrict__ flagsB)
{
    __shared__ unsigned short sWg[32 * PK];   // 98,816 B
    __shared__ unsigned short sWc[16 * PK];   // 49,408 B
    __shared__ float sU[2][16][17];           //  2,176 B
    __shared__ float sRed[2][16][17];         //  2,176 B  (total ~152.6 KB)

    const int b    = blockIdx.x;
    const int tid  = threadIdx.x;
    const int wid  = tid >> 6;
    const int lane = tid & 63;
    const int l15  = lane & 15;
    const int kq   = lane >> 4;
    const int rt   = wid >> 1;
    const int khalf= wid & 1;
    const int roff = rt * 16;
    const int arow = roff + l15;

    // ---- stage weight slices into LDS (once) ----
    {
        s8v* dst = (s8v*)sWg;
        for (int idx = tid; idx < 32 * K8; idx += TPB) {
            int c = idx / K8, k8 = idx % K8;
            int gc = (c < 16) ? (b * 16 + c) : (HH + b * 16 + (c - 16));
            dst[c * PK8 + k8] = ((const s8v*)(WgT + (size_t)gc * KK))[k8];
        }
        s8v* dst2 = (s8v*)sWc;
        for (int idx = tid; idx < 16 * K8; idx += TPB) {
            int c = idx / K8, k8 = idx % K8;
            dst2[c * PK8 + k8] = ((const s8v*)(WcT + (size_t)(b * 16 + c) * KK))[k8];
        }
    }

    const int   gcol = (khalf == 0) ? (b * 16 + l15) : (HH + b * 16 + l15);
    const float bgv  = bg[gcol];
    const int   ccol = b * 16 + l15;
    const float bcv  = bc[ccol];

    const s8v* sWg8 = (const s8v*)sWg;
    const s8v* sWc8 = (const s8v*)sWc;
    const s8v* bwg  = sWg8 + (khalf * 16 + l15) * PK8 + kq;  // gate weights (this wave's cols)
    const s8v* bwgh = bwg + DD / 8;                          // h-part
    const s8v* bwc  = sWc8 + l15 * PK8 + kq;                 // cand weights
    const s8v* bwch = bwc + DD / 8;                          // rh-part

    const u64* hq = (const u64*)(hbf  + (size_t)arow * HH) + kq * 2;
    const u64* rq = (const u64*)(rhbf + (size_t)arow * HH) + kq * 2;

    float hprev[4] = {0.f, 0.f, 0.f, 0.f};   // h_{t-1}[roff+kq*4+i][ccol] (khalf0 authoritative)

    __syncthreads();

#pragma unroll 1
    for (int t = 0; t < TT; ++t) {
        const s8v* xap = (const s8v*)(Xbf + (size_t)arow * (TT * DD) + (size_t)t * DD) + kq;

        // ---------- Phase A: gates. x-part before the wait ----------
        f4v a0 = {0.f, 0.f, 0.f, 0.f}, a1 = {0.f, 0.f, 0.f, 0.f};
#pragma unroll
        for (int kx = 0; kx < NCH_X; kx += 2) {
            a0 = MFMA(xap[kx * 4],       bwg[kx * 4],       a0);
            a1 = MFMA(xap[(kx + 1) * 4], bwg[(kx + 1) * 4], a1);
        }

        if (t > 0) {
            wait_flags(flagsB, t);           // h_{t-1} published by all blocks
            // h-GEMM: coherent loads, 4 groups of 8 chunks, 2-deep pipeline
            s8v h0[8], h1[8];
#pragma unroll
            for (int j = 0; j < 8; ++j) h0[j] = cload_chunk(hq + j * 8);
#pragma unroll
            for (int j = 0; j < 8; ++j) h1[j] = cload_chunk(hq + 64 + j * 8);
#pragma unroll
            for (int j = 0; j < 8; j += 2) {
                a0 = MFMA(h0[j],     bwgh[j * 4],       a0);
                a1 = MFMA(h0[j + 1], bwgh[(j + 1) * 4], a1);
            }
#pragma unroll
            for (int j = 0; j < 8; ++j) h0[j] = cload_chunk(hq + 128 + j * 8);
#pragma unroll
            for (int j = 0; j < 8; j += 2) {
                a0 = MFMA(h1[j],     bwgh[(8 + j) * 4], a0);
                a1 = MFMA(h1[j + 1], bwgh[(9 + j) * 4], a1);
            }
#pragma unroll
            for (int j = 0; j < 8; ++j) h1[j] = cload_chunk(hq + 192 + j * 8);
#pragma unroll
            for (int j = 0; j < 8; j += 2) {
                a0 = MFMA(h0[j],     bwgh[(16 + j) * 4], a0);
                a1 = MFMA(h0[j + 1], bwgh[(17 + j) * 4], a1);
            }
#pragma unroll
            for (int j = 0; j < 8; j += 2) {
                a0 = MFMA(h1[j],     bwgh[(24 + j) * 4], a0);
                a1 = MFMA(h1[j + 1], bwgh[(25 + j) * 4], a1);
            }
        }

        // epilogue A: khalf0 -> rh (coherent publish), khalf1 -> u (LDS)
#pragma unroll
        for (int i = 0; i < 4; ++i) {
            int row = roff + kq * 4 + i;
            float z = a0[i] + a1[i] + bgv;
            float g = 1.f / (1.f + __expf(-z));
            if (khalf == 0) {
                __hip_bfloat16 hb = __float2bfloat16(g * hprev[i]);
                cstore_short(rhbf + (size_t)row * HH + ccol, *(unsigned short*)&hb);
            } else {
                sU[rt][kq * 4 + i][l15] = g;
            }
        }
        asm volatile("s_waitcnt vmcnt(0)" ::: "memory");   // rh stores at coherence point
        __syncthreads();
        if (tid == 0 && t > 0)
            __hip_atomic_store(&flagsA[b], t, __ATOMIC_RELAXED, __HIP_MEMORY_SCOPE_AGENT);

        // ---------- Phase B: candidate. x-part (K-split) before the wait ----------
        f4v c0 = {0.f, 0.f, 0.f, 0.f}, c1 = {0.f, 0.f, 0.f, 0.f};
        const int xbase = khalf * 8;
#pragma unroll
        for (int kx = 0; kx < 8; kx += 2) {
            c0 = MFMA(xap[(xbase + kx) * 4],     bwc[(xbase + kx) * 4],     c0);
            c1 = MFMA(xap[(xbase + kx + 1) * 4], bwc[(xbase + kx + 1) * 4], c1);
        }

        if (t > 0) {
            wait_flags(flagsA, t);           // rh published by all blocks
            const int rbase = khalf * 16;    // this wave's 16 rh k-chunks
            const u64* rqq = rq + (size_t)rbase * 8;
            s8v r0[8], r1[8];
#pragma unroll
            for (int j = 0; j < 8; ++j) r0[j] = cload_chunk(rqq + j * 8);
#pragma unroll
            for (int j = 0; j < 8; ++j) r1[j] = cload_chunk(rqq + 64 + j * 8);
#pragma unroll
            for (int j = 0; j < 8; j += 2) {
                c0 = MFMA(r0[j],     bwch[(rbase + j) * 4],     c0);
                c1 = MFMA(r0[j + 1], bwch[(rbase + j + 1) * 4], c1);
            }
#pragma unroll
            for (int j = 0; j < 8; j += 2) {
                c0 = MFMA(r1[j],     bwch[(rbase + 8 + j) * 4],     c0);
                c1 = MFMA(r1[j + 1], bwch[(rbase + 8 + j + 1) * 4], c1);
            }
        }
        f4v c2 = c0 + c1;

        if (khalf == 1) {
#pragma unroll
            for (int i = 0; i < 4; ++i) sRed[rt][kq * 4 + i][l15] = c2[i];
        }
        __syncthreads();
        if (khalf == 0) {
#pragma unroll
            for (int i = 0; i < 4; ++i) {
                int row = roff + kq * 4 + i;
                float z = c2[i] + sRed[rt][kq * 4 + i][l15] + bcv;
                float e = __expf(2.f * z);
                float cv = 1.f - 2.f / (e + 1.f);
                float uvv = sU[rt][kq * 4 + i][l15];
                float hn = uvv * hprev[i] + (1.f - uvv) * cv;
                out[(size_t)row * (TT * HH) + (size_t)t * HH + ccol] = hn;  // plain store
                __hip_bfloat16 hb = __float2bfloat16(hn);
                cstore_short(hbf + (size_t)row * HH + ccol, *(unsigned short*)&hb);
                hprev[i] = hn;
            }
        }
        asm volatile("s_waitcnt vmcnt(0)" ::: "memory");   // h stores at coherence point
        __syncthreads();
        if (tid == 0)
            __hip_atomic_store(&flagsB[b], t + 1, __ATOMIC_RELAXED, __HIP_MEMORY_SCOPE_AGENT);
    }
}

// ---------------------------------------------------------------------------
extern "C" void kernel_launch(void* const* d_in, const int* in_sizes, int n_in,
                              void* d_out, int out_size, void* d_ws, size_t ws_size,
                              hipStream_t stream) {
    const float* X  = (const float*)d_in[0];
    const float* gk = (const float*)d_in[1];
    const float* gb = (const float*)d_in[2];
    const float* ck = (const float*)d_in[3];
    const float* cb = (const float*)d_in[4];
    float* out = (float*)d_out;
    char* ws = (char*)d_ws;
    if (ws_size < OFF_FLG + SZ_FLG) return;

    unsigned short* WgT  = (unsigned short*)(ws + OFF_WGT);
    unsigned short* WcT  = (unsigned short*)(ws + OFF_WCT);
    unsigned short* Xbf  = (unsigned short*)(ws + OFF_XBF);
    unsigned short* hbf  = (unsigned short*)(ws + OFF_HBF);
    unsigned short* rhbf = (unsigned short*)(ws + OFF_RHB);
    int*            flagsA = (int*)(ws + OFF_FLG);
    int*            flagsB = flagsA + NBLK;

    hipMemsetAsync(flagsA, 0, SZ_FLG, stream);

    dim3 tb(TPB);
    wtr_kernel<<<dim3(2 * HH / 32, KK / 32), tb, 0, stream>>>(gk, WgT, 2 * HH);
    wtr_kernel<<<dim3(HH / 32, KK / 32), tb, 0, stream>>>(ck, WcT, HH);
    xconv_kernel<<<(BB * TT * DD) / (TPB * 4), tb, 0, stream>>>(X, Xbf);

    gru_kernel<<<NBLK, tb, 0, stream>>>(Xbf, WgT, WcT, gb, cb, out,
                                        hbf, rhbf, flagsA, flagsB);
}

// Round 4
// 5831.020 us; speedup vs baseline: 2.3104x; 1.4438x over previous
//
#include <hip/hip_runtime.h>
#include <hip/hip_bf16.h>

typedef short s8v __attribute__((ext_vector_type(8)));
typedef float f4v __attribute__((ext_vector_type(4)));
typedef unsigned int u4v __attribute__((ext_vector_type(4)));
typedef unsigned int u2v __attribute__((ext_vector_type(2)));

#define NBLK 64
#define TPB 256

constexpr int BB = 32, TT = 512, DD = 512, HH = 1024;
constexpr int KK = DD + HH;          // 1536
constexpr int PK = KK + 8;           // padded LDS K-stride
constexpr int PK8 = PK / 8;
constexpr int K8 = KK / 8;
constexpr int NCH_X = DD / 32;       // 16 x-chunks

// ---- workspace layout (bytes) ----
constexpr size_t OFF_WGT = 0;
constexpr size_t SZ_WGT  = (size_t)2 * HH * KK * 2;
constexpr size_t OFF_WCT = OFF_WGT + SZ_WGT;
constexpr size_t SZ_WCT  = (size_t)HH * KK * 2;
constexpr size_t OFF_XBF = OFF_WCT + SZ_WCT;
constexpr size_t SZ_XBF  = (size_t)BB * TT * DD * 2;
constexpr size_t OFF_HBF = OFF_XBF + SZ_XBF;
constexpr size_t SZ_HBF  = (size_t)BB * HH * 2;
constexpr size_t OFF_RHB = OFF_HBF + SZ_HBF;
constexpr size_t SZ_RHB  = (size_t)BB * HH * 2;
constexpr size_t OFF_FLG = OFF_RHB + SZ_RHB;
constexpr size_t SZ_FLG  = (size_t)2 * NBLK * 4;

// ---------------------------------------------------------------------------
__global__ void wtr_kernel(const float* __restrict__ in, unsigned short* __restrict__ out, int N) {
    __shared__ float tl[32][33];
    int tx = threadIdx.x & 31, ty = threadIdx.x >> 5;
    int n0 = blockIdx.x * 32, k0 = blockIdx.y * 32;
#pragma unroll
    for (int r = ty; r < 32; r += 8) tl[r][tx] = in[(size_t)(k0 + r) * N + n0 + tx];
    __syncthreads();
#pragma unroll
    for (int r = ty; r < 32; r += 8) {
        __hip_bfloat16 h = __float2bfloat16(tl[tx][r]);
        out[(size_t)(n0 + r) * KK + k0 + tx] = *reinterpret_cast<unsigned short*>(&h);
    }
}

__global__ void xconv_kernel(const float* __restrict__ X, unsigned short* __restrict__ Xbf) {
    size_t i = ((size_t)blockIdx.x * TPB + threadIdx.x) * 4;
    float4 v = *reinterpret_cast<const float4*>(X + i);
    __hip_bfloat16 h0 = __float2bfloat16(v.x), h1 = __float2bfloat16(v.y);
    __hip_bfloat16 h2 = __float2bfloat16(v.z), h3 = __float2bfloat16(v.w);
    ushort4 o;
    o.x = *(unsigned short*)&h0; o.y = *(unsigned short*)&h1;
    o.z = *(unsigned short*)&h2; o.w = *(unsigned short*)&h3;
    *reinterpret_cast<ushort4*>(Xbf + i) = o;
}

// ---------------------------------------------------------------------------
// Coherent access primitives (L1/L2-bypassing, served at the agent coherence
// point). No fences anywhere: exchanged data itself travels coherently.
__device__ __forceinline__ u4v cload16(const void* p) {
    u4v r;
    asm volatile("global_load_dwordx4 %0, %1, off sc0 sc1" : "=v"(r) : "v"(p) : "memory");
    return r;
}
__device__ __forceinline__ void cstore8(void* p, u2v v) {
    asm volatile("global_store_dwordx2 %0, %1, off sc0 sc1" :: "v"(p), "v"(v) : "memory");
}
#define B16(x) __builtin_bit_cast(s8v, (x))
#define WAIT_VM(n) do { asm volatile("s_waitcnt vmcnt(" #n ")" ::: "memory"); \
                        __builtin_amdgcn_sched_barrier(0); } while (0)

__device__ __forceinline__ void wait_flags(int* f, int gen) {
    if (threadIdx.x < NBLK) {
        while (__hip_atomic_load(&f[threadIdx.x], __ATOMIC_RELAXED,
                                 __HIP_MEMORY_SCOPE_AGENT) < gen) {
            __builtin_amdgcn_s_sleep(1);
        }
    }
    __syncthreads();
    asm volatile("" ::: "memory");
}

#define MFMA(A, B, C) __builtin_amdgcn_mfma_f32_16x16x32_bf16((A), (B), (C), 0, 0, 0)

// ---------------------------------------------------------------------------
// Persistent kernel, 64 blocks x 256 threads (4 waves), 1 block/CU.
// Block b owns r-cols, u-cols and candidate-cols [b*16, b*16+16); h_prev for
// its columns lives in registers across all 512 steps.
// Waves: wid = rt*2 + khalf; rt = batch-row tile (16 rows each).
//   Phase A: khalf0 -> r cols, khalf1 -> u cols (each full K).
//   Phase B: khalf splits K of the candidate GEMM.
__global__ __launch_bounds__(TPB, 1) void gru_kernel(
    const unsigned short* __restrict__ Xbf,
    const unsigned short* __restrict__ WgT,
    const unsigned short* __restrict__ WcT,
    const float* __restrict__ bg,
    const float* __restrict__ bc,
    float* __restrict__ out,
    unsigned short* __restrict__ hbf,
    unsigned short* __restrict__ rhbf,
    int* __restrict__ flagsA,
    int* __restrict__ flagsB)
{
    __shared__ unsigned short sWg[32 * PK];   // 98,816 B
    __shared__ unsigned short sWc[16 * PK];   // 49,408 B
    __shared__ float sU[2][16][17];           //  2,176 B
    __shared__ float sRed[2][16][17];         //  2,176 B
    __shared__ unsigned short sSRH[32][16];   //  1,024 B (rh row-major stage)
    __shared__ unsigned short sSH[32][16];    //  1,024 B (h  row-major stage)

    const int b    = blockIdx.x;
    const int tid  = threadIdx.x;
    const int wid  = tid >> 6;
    const int lane = tid & 63;
    const int l15  = lane & 15;
    const int kq   = lane >> 4;
    const int rt   = wid >> 1;
    const int khalf= wid & 1;
    const int roff = rt * 16;
    const int arow = roff + l15;
    const int bcol0= b * 16;

    // ---- stage weight slices into LDS (once) ----
    {
        s8v* dst = (s8v*)sWg;
        for (int idx = tid; idx < 32 * K8; idx += TPB) {
            int c = idx / K8, k8 = idx % K8;
            int gc = (c < 16) ? (bcol0 + c) : (HH + bcol0 + (c - 16));
            dst[c * PK8 + k8] = ((const s8v*)(WgT + (size_t)gc * KK))[k8];
        }
        s8v* dst2 = (s8v*)sWc;
        for (int idx = tid; idx < 16 * K8; idx += TPB) {
            int c = idx / K8, k8 = idx % K8;
            dst2[c * PK8 + k8] = ((const s8v*)(WcT + (size_t)(bcol0 + c) * KK))[k8];
        }
    }

    const int   gcol = (khalf == 0) ? (bcol0 + l15) : (HH + bcol0 + l15);
    const float bgv  = bg[gcol];
    const int   ccol = bcol0 + l15;
    const float bcv  = bc[ccol];

    const s8v* sWg8 = (const s8v*)sWg;
    const s8v* sWc8 = (const s8v*)sWc;
    const s8v* bwg  = sWg8 + (khalf * 16 + l15) * PK8 + kq;  // gate W (this wave's cols)
    const s8v* bwgh = bwg + DD / 8;                          // h-part
    const s8v* bwc  = sWc8 + l15 * PK8 + kq;                 // cand W
    const s8v* bwch = bwc + DD / 8;                          // rh-part

    float hprev[4] = {0.f, 0.f, 0.f, 0.f};   // h_{t-1}[roff+kq*4+i][ccol]

    __syncthreads();

#pragma unroll 1
    for (int t = 0; t < TT; ++t) {
        const s8v* xap = (const s8v*)(Xbf + (size_t)arow * (TT * DD) + (size_t)t * DD) + kq;

        // ========== Phase A: gates. x-part before the wait ==========
        f4v a0 = {0.f, 0.f, 0.f, 0.f}, a1 = {0.f, 0.f, 0.f, 0.f};
#pragma unroll
        for (int kx = 0; kx < NCH_X; kx += 2) {
            a0 = MFMA(xap[kx * 4],       bwg[kx * 4],       a0);
            a1 = MFMA(xap[(kx + 1) * 4], bwg[(kx + 1) * 4], a1);
        }

        if (t > 0) {
            wait_flags(flagsB, t);           // h_{t-1} published by all blocks
            WAIT_VM(0);                      // clean vmcnt baseline for counted region
            const unsigned short* hp = hbf + (size_t)arow * HH + kq * 8;
            u4v hb[16];
#pragma unroll
            for (int j = 0; j < 8; ++j) hb[j]     = cload16(hp + (size_t)j * 32);
#pragma unroll
            for (int j = 0; j < 8; ++j) hb[8 + j] = cload16(hp + (size_t)(8 + j) * 32);
            WAIT_VM(8);                      // batch0 complete
#pragma unroll
            for (int j = 0; j < 8; j += 2) {
                a0 = MFMA(B16(hb[j]),     bwgh[j * 4],       a0);
                a1 = MFMA(B16(hb[j + 1]), bwgh[(j + 1) * 4], a1);
            }
#pragma unroll
            for (int j = 0; j < 8; ++j) hb[j] = cload16(hp + (size_t)(16 + j) * 32);
            WAIT_VM(8);                      // batch1 complete
#pragma unroll
            for (int j = 0; j < 8; j += 2) {
                a0 = MFMA(B16(hb[8 + j]),     bwgh[(8 + j) * 4], a0);
                a1 = MFMA(B16(hb[8 + j + 1]), bwgh[(9 + j) * 4], a1);
            }
#pragma unroll
            for (int j = 0; j < 8; ++j) hb[8 + j] = cload16(hp + (size_t)(24 + j) * 32);
            WAIT_VM(8);                      // batch2 complete
#pragma unroll
            for (int j = 0; j < 8; j += 2) {
                a0 = MFMA(B16(hb[j]),     bwgh[(16 + j) * 4], a0);
                a1 = MFMA(B16(hb[j + 1]), bwgh[(17 + j) * 4], a1);
            }
            WAIT_VM(0);                      // batch3 complete
#pragma unroll
            for (int j = 0; j < 8; j += 2) {
                a0 = MFMA(B16(hb[8 + j]),     bwgh[(24 + j) * 4], a0);
                a1 = MFMA(B16(hb[8 + j + 1]), bwgh[(25 + j) * 4], a1);
            }
        }

        // epilogue A: khalf0 -> rh into LDS stage, khalf1 -> u into LDS
#pragma unroll
        for (int i = 0; i < 4; ++i) {
            float z = a0[i] + a1[i] + bgv;
            float g = 1.f / (1.f + __expf(-z));
            if (khalf == 0) {
                __hip_bfloat16 hb16 = __float2bfloat16(g * hprev[i]);
                sSRH[roff + kq * 4 + i][l15] = *(unsigned short*)&hb16;
            } else {
                sU[rt][kq * 4 + i][l15] = g;
            }
        }
        __syncthreads();
        // coalesced coherent publish of rh (row-major, 8B per thread)
        if (tid < 128) {
            int row = tid >> 2, c4 = (tid & 3) << 2;
            u2v v = *reinterpret_cast<const u2v*>(&sSRH[row][c4]);
            cstore8(rhbf + (size_t)row * HH + bcol0 + c4, v);
        }
        asm volatile("s_waitcnt vmcnt(0)" ::: "memory");
        __syncthreads();
        if (tid == 0 && t > 0)
            __hip_atomic_store(&flagsA[b], t, __ATOMIC_RELAXED, __HIP_MEMORY_SCOPE_AGENT);

        // ========== Phase B: candidate. x-part (K-split) before the wait ==========
        f4v c0 = {0.f, 0.f, 0.f, 0.f}, c1 = {0.f, 0.f, 0.f, 0.f};
        const int xbase = khalf * 8;
#pragma unroll
        for (int kx = 0; kx < 8; kx += 2) {
            c0 = MFMA(xap[(xbase + kx) * 4],     bwc[(xbase + kx) * 4],     c0);
            c1 = MFMA(xap[(xbase + kx + 1) * 4], bwc[(xbase + kx + 1) * 4], c1);
        }

        if (t > 0) {
            wait_flags(flagsA, t);           // rh published by all blocks
            WAIT_VM(0);
            const int rbase = khalf * 16;    // this wave's 16 rh k-chunks
            const unsigned short* rp = rhbf + (size_t)arow * HH + (size_t)rbase * 32 + kq * 8;
            u4v rb[16];
#pragma unroll
            for (int j = 0; j < 8; ++j) rb[j]     = cload16(rp + (size_t)j * 32);
#pragma unroll
            for (int j = 0; j < 8; ++j) rb[8 + j] = cload16(rp + (size_t)(8 + j) * 32);
            WAIT_VM(8);
#pragma unroll
            for (int j = 0; j < 8; j += 2) {
                c0 = MFMA(B16(rb[j]),     bwch[(rbase + j) * 4],     c0);
                c1 = MFMA(B16(rb[j + 1]), bwch[(rbase + j + 1) * 4], c1);
            }
            WAIT_VM(0);
#pragma unroll
            for (int j = 0; j < 8; j += 2) {
                c0 = MFMA(B16(rb[8 + j]),     bwch[(rbase + 8 + j) * 4],     c0);
                c1 = MFMA(B16(rb[8 + j + 1]), bwch[(rbase + 8 + j + 1) * 4], c1);
            }
        }
        f4v c2 = c0 + c1;

        if (khalf == 1) {
#pragma unroll
            for (int i = 0; i < 4; ++i) sRed[rt][kq * 4 + i][l15] = c2[i];
        }
        __syncthreads();
        if (khalf == 0) {
#pragma unroll
            for (int i = 0; i < 4; ++i) {
                int row = roff + kq * 4 + i;
                float z = c2[i] + sRed[rt][kq * 4 + i][l15] + bcv;
                float e = __expf(2.f * z);
                float cv = 1.f - 2.f / (e + 1.f);
                float uvv = sU[rt][kq * 4 + i][l15];
                float hn = uvv * hprev[i] + (1.f - uvv) * cv;
                out[(size_t)row * (TT * HH) + (size_t)t * HH + ccol] = hn;  // cached store
                __hip_bfloat16 hb16 = __float2bfloat16(hn);
                sSH[row][l15] = *(unsigned short*)&hb16;
                hprev[i] = hn;
            }
        }
        __syncthreads();
        // coalesced coherent publish of h (row-major, 8B per thread)
        if (tid < 128) {
            int row = tid >> 2, c4 = (tid & 3) << 2;
            u2v v = *reinterpret_cast<const u2v*>(&sSH[row][c4]);
            cstore8(hbf + (size_t)row * HH + bcol0 + c4, v);
        }
        asm volatile("s_waitcnt vmcnt(0)" ::: "memory");
        __syncthreads();
        if (tid == 0)
            __hip_atomic_store(&flagsB[b], t + 1, __ATOMIC_RELAXED, __HIP_MEMORY_SCOPE_AGENT);
    }
}

// ---------------------------------------------------------------------------
extern "C" void kernel_launch(void* const* d_in, const int* in_sizes, int n_in,
                              void* d_out, int out_size, void* d_ws, size_t ws_size,
                              hipStream_t stream) {
    const float* X  = (const float*)d_in[0];
    const float* gk = (const float*)d_in[1];
    const float* gb = (const float*)d_in[2];
    const float* ck = (const float*)d_in[3];
    const float* cb = (const float*)d_in[4];
    float* out = (float*)d_out;
    char* ws = (char*)d_ws;
    if (ws_size < OFF_FLG + SZ_FLG) return;

    unsigned short* WgT  = (unsigned short*)(ws + OFF_WGT);
    unsigned short* WcT  = (unsigned short*)(ws + OFF_WCT);
    unsigned short* Xbf  = (unsigned short*)(ws + OFF_XBF);
    unsigned short* hbf  = (unsigned short*)(ws + OFF_HBF);
    unsigned short* rhbf = (unsigned short*)(ws + OFF_RHB);
    int*            flagsA = (int*)(ws + OFF_FLG);
    int*            flagsB = flagsA + NBLK;

    hipMemsetAsync(flagsA, 0, SZ_FLG, stream);

    dim3 tb(TPB);
    wtr_kernel<<<dim3(2 * HH / 32, KK / 32), tb, 0, stream>>>(gk, WgT, 2 * HH);
    wtr_kernel<<<dim3(HH / 32, KK / 32), tb, 0, stream>>>(ck, WcT, HH);
    xconv_kernel<<<(BB * TT * DD) / (TPB * 4), tb, 0, stream>>>(X, Xbf);

    gru_kernel<<<NBLK, tb, 0, stream>>>(Xbf, WgT, WcT, gb, cb, out,
                                        hbf, rhbf, flagsA, flagsB);
}

// Round 6
// 4541.302 us; speedup vs baseline: 2.9665x; 1.2840x over previous
//
#include <hip/hip_runtime.h>
#include <hip/hip_bf16.h>

typedef short s8v __attribute__((ext_vector_type(8)));
typedef float f4v __attribute__((ext_vector_type(4)));
typedef unsigned int u4v __attribute__((ext_vector_type(4)));
typedef unsigned int u2v __attribute__((ext_vector_type(2)));

#define NBLK 64
#define TPB 512

constexpr int BB = 32, TT = 512, DD = 512, HH = 1024;
constexpr int KK = DD + HH;          // 1536
constexpr int PK = KK + 8;           // padded LDS K-stride
constexpr int PK8 = PK / 8;
constexpr int K8 = KK / 8;

// ---- workspace layout (bytes) ----
constexpr size_t OFF_WGT = 0;
constexpr size_t SZ_WGT  = (size_t)2 * HH * KK * 2;
constexpr size_t OFF_WCT = OFF_WGT + SZ_WGT;
constexpr size_t SZ_WCT  = (size_t)HH * KK * 2;
constexpr size_t OFF_XBF = OFF_WCT + SZ_WCT;
constexpr size_t SZ_XBF  = (size_t)BB * TT * DD * 2;
constexpr size_t OFF_HPB = OFF_XBF + SZ_XBF;                    // h publish (IF)
constexpr size_t SZ_PUB  = (size_t)BB * HH * 2;
constexpr size_t OFF_RPB = OFF_HPB + SZ_PUB;                    // rh publish (IF)
constexpr size_t OFF_FLG = OFF_RPB + SZ_PUB;                    // gflagA[1024] gflagB[1024]
constexpr size_t SZ_FLG  = (size_t)2 * NBLK * 16 * 4;           // 8192

// ---------------------------------------------------------------------------
__global__ void wtr_kernel(const float* __restrict__ in, unsigned short* __restrict__ out, int N) {
    __shared__ float tl[32][33];
    int tx = threadIdx.x & 31, ty = threadIdx.x >> 5;
    int n0 = blockIdx.x * 32, k0 = blockIdx.y * 32;
#pragma unroll
    for (int r = ty; r < 32; r += 8) tl[r][tx] = in[(size_t)(k0 + r) * N + n0 + tx];
    __syncthreads();
#pragma unroll
    for (int r = ty; r < 32; r += 8) {
        __hip_bfloat16 h = __float2bfloat16(tl[tx][r]);
        out[(size_t)(n0 + r) * KK + k0 + tx] = *reinterpret_cast<unsigned short*>(&h);
    }
}

__global__ void xconv_kernel(const float* __restrict__ X, unsigned short* __restrict__ Xbf) {
    size_t i = ((size_t)blockIdx.x * 256 + threadIdx.x) * 4;
    float4 v = *reinterpret_cast<const float4*>(X + i);
    __hip_bfloat16 h0 = __float2bfloat16(v.x), h1 = __float2bfloat16(v.y);
    __hip_bfloat16 h2 = __float2bfloat16(v.z), h3 = __float2bfloat16(v.w);
    ushort4 o;
    o.x = *(unsigned short*)&h0; o.y = *(unsigned short*)&h1;
    o.z = *(unsigned short*)&h2; o.w = *(unsigned short*)&h3;
    *reinterpret_cast<ushort4*>(Xbf + i) = o;
}

// ---------------------------------------------------------------------------
// Proven coherent primitives (r2-r4): agent-scope atomics for flags, sc0 sc1
// (device-coherent point) for exchanged data. NO other cache-scope tricks.
__device__ __forceinline__ u4v cload16(const void* p) {
    u4v r; asm volatile("global_load_dwordx4 %0, %1, off sc0 sc1" : "=v"(r) : "v"(p) : "memory"); return r;
}
__device__ __forceinline__ void cstore8(void* p, u2v v) {
    asm volatile("global_store_dwordx2 %0, %1, off sc0 sc1" :: "v"(p), "v"(v) : "memory");
}
#define B16(x) __builtin_bit_cast(s8v, (x))
#define WAIT_VM(n) do { asm volatile("s_waitcnt vmcnt(" #n ")" ::: "memory"); \
                        __builtin_amdgcn_sched_barrier(0); } while (0)

__device__ __forceinline__ void wait_flags(int* f, int gen) {
    if (threadIdx.x < NBLK) {
        while (__hip_atomic_load(&f[threadIdx.x * 16], __ATOMIC_RELAXED,
                                 __HIP_MEMORY_SCOPE_AGENT) < gen) {
            __builtin_amdgcn_s_sleep(1);
        }
    }
    __syncthreads();
    asm volatile("" ::: "memory");
}

#define MFMA(A, B, C) __builtin_amdgcn_mfma_f32_16x16x32_bf16((A), (B), (C), 0, 0, 0)

// ---------------------------------------------------------------------------
// Persistent kernel, 64 blocks x 512 threads (8 waves), 1 block/CU.
// Block b owns r/u/cand columns [b*16, b*16+16). hprev + u live in registers
// of the ks==0 waves. Waves: wid = rt*4 + ks; rt = batch-row tile (16 rows),
// ks = 4-way K-split (x chunks [4ks,4ks+4), h/rh chunks [8ks,8ks+8)).
// Cross-wave K-reduction via 2-slot LDS partials (2 syncthreads).
__global__ __launch_bounds__(TPB, 1) void gru_kernel(
    const unsigned short* __restrict__ Xbf,
    const unsigned short* __restrict__ WgT,
    const unsigned short* __restrict__ WcT,
    const float* __restrict__ bg,
    const float* __restrict__ bc,
    float* __restrict__ out,
    unsigned short* __restrict__ hpub,
    unsigned short* __restrict__ rpub,
    int* __restrict__ gflagA,
    int* __restrict__ gflagB)
{
    __shared__ unsigned short sWg[32 * PK];   // 98,816 B
    __shared__ unsigned short sWc[16 * PK];   // 49,408 B
    __shared__ float sP[2][2][2][16][17];     //  8,704 B  [slot][rt][cg][row][col]
    __shared__ unsigned short sSRH[32][16];   //  1,024 B
    __shared__ unsigned short sSH[32][16];    //  1,024 B   total 158,976

    const int b    = blockIdx.x;
    const int tid  = threadIdx.x;
    const int wid  = tid >> 6;
    const int lane = tid & 63;
    const int l15  = lane & 15;
    const int lq   = lane >> 4;
    const int rt   = wid >> 2;
    const int ks   = wid & 3;
    const int roff = rt * 16;
    const int arow = roff + l15;
    const int bcol0= b * 16;

    // ---- stage weight slices into LDS (once) ----
    {
        s8v* dst = (s8v*)sWg;
        for (int idx = tid; idx < 32 * K8; idx += TPB) {
            int c = idx / K8, k8 = idx % K8;
            int gc = (c < 16) ? (bcol0 + c) : (HH + bcol0 + (c - 16));
            dst[c * PK8 + k8] = ((const s8v*)(WgT + (size_t)gc * KK))[k8];
        }
        s8v* dst2 = (s8v*)sWc;
        for (int idx = tid; idx < 16 * K8; idx += TPB) {
            int c = idx / K8, k8 = idx % K8;
            dst2[c * PK8 + k8] = ((const s8v*)(WcT + (size_t)(bcol0 + c) * KK))[k8];
        }
    }

    const float bgr = bg[bcol0 + l15];        // r bias
    const float bgu = bg[HH + bcol0 + l15];   // u bias
    const float bcv = bc[bcol0 + l15];
    const int   ccol = bcol0 + l15;

    const s8v* sWg8 = (const s8v*)sWg;
    const s8v* sWc8 = (const s8v*)sWc;
    const s8v* bwr = sWg8 + l15 * PK8 + lq;          // r-col weights
    const s8v* bwu = sWg8 + (16 + l15) * PK8 + lq;   // u-col weights
    const s8v* bwc = sWc8 + l15 * PK8 + lq;          // cand weights
    // per-wave chunk bases (s8v units; 1 chunk = 4 s8v)
    const s8v* bwrx = bwr + 16 * ks;                 // x chunks [4ks..4ks+4)
    const s8v* bwux = bwu + 16 * ks;
    const s8v* bwrh = bwr + 64 + 32 * ks;            // h chunks [8ks..8ks+8)
    const s8v* bwuh = bwu + 64 + 32 * ks;
    const s8v* bwcx = bwc + 16 * ks;
    const s8v* bwch = bwc + 64 + 32 * ks;

    float hprev[4] = {0.f, 0.f, 0.f, 0.f};   // valid in ks==0 waves
    float ureg[4]  = {0.f, 0.f, 0.f, 0.f};

    __syncthreads();

#pragma unroll 1
    for (int t = 0; t < TT; ++t) {
        const s8v* xk = (const s8v*)(Xbf + (size_t)arow * (TT * DD) + (size_t)t * DD) + lq + 16 * ks;

        // ========== Phase A: gates (4-way K-split). x-part before the wait ==========
        f4v ar0 = {0,0,0,0}, ar1 = {0,0,0,0}, au0 = {0,0,0,0}, au1 = {0,0,0,0};
        {
            s8v x0 = xk[0], x1 = xk[4], x2 = xk[8], x3 = xk[12];
            ar0 = MFMA(x0, bwrx[0],  ar0); au0 = MFMA(x0, bwux[0],  au0);
            ar1 = MFMA(x1, bwrx[4],  ar1); au1 = MFMA(x1, bwux[4],  au1);
            ar0 = MFMA(x2, bwrx[8],  ar0); au0 = MFMA(x2, bwux[8],  au0);
            ar1 = MFMA(x3, bwrx[12], ar1); au1 = MFMA(x3, bwux[12], au1);
        }

        if (t > 0) {
            wait_flags(gflagB, t);               // h_{t-1} at the coherence point
            WAIT_VM(0);
            const unsigned short* hp = hpub + (size_t)arow * HH + ks * 256 + lq * 8;
            u4v hb[8];
#pragma unroll
            for (int j = 0; j < 8; ++j) hb[j] = cload16(hp + (size_t)j * 32);
            WAIT_VM(4);
            ar0 = MFMA(B16(hb[0]), bwrh[0],  ar0); au0 = MFMA(B16(hb[0]), bwuh[0],  au0);
            ar1 = MFMA(B16(hb[1]), bwrh[4],  ar1); au1 = MFMA(B16(hb[1]), bwuh[4],  au1);
            ar0 = MFMA(B16(hb[2]), bwrh[8],  ar0); au0 = MFMA(B16(hb[2]), bwuh[8],  au0);
            ar1 = MFMA(B16(hb[3]), bwrh[12], ar1); au1 = MFMA(B16(hb[3]), bwuh[12], au1);
            WAIT_VM(0);
            ar0 = MFMA(B16(hb[4]), bwrh[16], ar0); au0 = MFMA(B16(hb[4]), bwuh[16], au0);
            ar1 = MFMA(B16(hb[5]), bwrh[20], ar1); au1 = MFMA(B16(hb[5]), bwuh[20], au1);
            ar0 = MFMA(B16(hb[6]), bwrh[24], ar0); au0 = MFMA(B16(hb[6]), bwuh[24], au0);
            ar1 = MFMA(B16(hb[7]), bwrh[28], ar1); au1 = MFMA(B16(hb[7]), bwuh[28], au1);
        }

        // ---- cross-wave K-reduction (2 slots, 2 barriers) ----
        f4v pr = ar0 + ar1, pu = au0 + au1;
        if (ks & 1) {
            int sl = ks >> 1;
#pragma unroll
            for (int i = 0; i < 4; ++i) {
                sP[sl][rt][0][lq * 4 + i][l15] = pr[i];
                sP[sl][rt][1][lq * 4 + i][l15] = pu[i];
            }
        }
        __syncthreads();
        if (!(ks & 1)) {
            int sl = ks >> 1;
#pragma unroll
            for (int i = 0; i < 4; ++i) {
                pr[i] += sP[sl][rt][0][lq * 4 + i][l15];
                pu[i] += sP[sl][rt][1][lq * 4 + i][l15];
            }
        }
        if (ks == 2) {       // re-writes its OWN slot (1); no reader until next barrier
#pragma unroll
            for (int i = 0; i < 4; ++i) {
                sP[1][rt][0][lq * 4 + i][l15] = pr[i];
                sP[1][rt][1][lq * 4 + i][l15] = pu[i];
            }
        }
        __syncthreads();
        if (ks == 0) {
#pragma unroll
            for (int i = 0; i < 4; ++i) {
                float zr = pr[i] + sP[1][rt][0][lq * 4 + i][l15] + bgr;
                float zu = pu[i] + sP[1][rt][1][lq * 4 + i][l15] + bgu;
                float r = 1.f / (1.f + __expf(-zr));
                ureg[i] = 1.f / (1.f + __expf(-zu));
                __hip_bfloat16 hb16 = __float2bfloat16(r * hprev[i]);
                sSRH[roff + lq * 4 + i][l15] = *(unsigned short*)&hb16;
            }
        }
        __syncthreads();
        if (t > 0) {         // rh_0 == 0, never read
            if (tid < 128) {
                int row = tid >> 2, c4 = (tid & 3) << 2;
                u2v v = *reinterpret_cast<const u2v*>(&sSRH[row][c4]);
                cstore8(rpub + (size_t)row * HH + bcol0 + c4, v);
            }
            asm volatile("s_waitcnt vmcnt(0)" ::: "memory");
            __syncthreads();
            if (tid == 0)
                __hip_atomic_store(&gflagA[b * 16], t, __ATOMIC_RELAXED, __HIP_MEMORY_SCOPE_AGENT);
        }

        // ========== Phase B: candidate (4-way K-split). x-part before the wait ==========
        f4v c0 = {0,0,0,0}, c1 = {0,0,0,0};
        {
            s8v x0 = xk[0], x1 = xk[4], x2 = xk[8], x3 = xk[12];
            c0 = MFMA(x0, bwcx[0],  c0); c1 = MFMA(x1, bwcx[4],  c1);
            c0 = MFMA(x2, bwcx[8],  c0); c1 = MFMA(x3, bwcx[12], c1);
        }

        if (t > 0) {
            wait_flags(gflagA, t);               // rh_t at the coherence point
            WAIT_VM(0);
            const unsigned short* rp = rpub + (size_t)arow * HH + ks * 256 + lq * 8;
            u4v rb[8];
#pragma unroll
            for (int j = 0; j < 8; ++j) rb[j] = cload16(rp + (size_t)j * 32);
            WAIT_VM(4);
            c0 = MFMA(B16(rb[0]), bwch[0],  c0); c1 = MFMA(B16(rb[1]), bwch[4],  c1);
            c0 = MFMA(B16(rb[2]), bwch[8],  c0); c1 = MFMA(B16(rb[3]), bwch[12], c1);
            WAIT_VM(0);
            c0 = MFMA(B16(rb[4]), bwch[16], c0); c1 = MFMA(B16(rb[5]), bwch[20], c1);
            c0 = MFMA(B16(rb[6]), bwch[24], c0); c1 = MFMA(B16(rb[7]), bwch[28], c1);
        }

        f4v pc = c0 + c1;
        if (ks & 1) {
            int sl = ks >> 1;
#pragma unroll
            for (int i = 0; i < 4; ++i) sP[sl][rt][0][lq * 4 + i][l15] = pc[i];
        }
        __syncthreads();
        if (!(ks & 1)) {
            int sl = ks >> 1;
#pragma unroll
            for (int i = 0; i < 4; ++i) pc[i] += sP[sl][rt][0][lq * 4 + i][l15];
        }
        if (ks == 2) {
#pragma unroll
            for (int i = 0; i < 4; ++i) sP[1][rt][0][lq * 4 + i][l15] = pc[i];
        }
        __syncthreads();
        if (ks == 0) {
#pragma unroll
            for (int i = 0; i < 4; ++i) {
                int row = roff + lq * 4 + i;
                float z = pc[i] + sP[1][rt][0][lq * 4 + i][l15] + bcv;
                float e = __expf(2.f * z);
                float cv = 1.f - 2.f / (e + 1.f);
                float hn = ureg[i] * hprev[i] + (1.f - ureg[i]) * cv;
                out[(size_t)row * (TT * HH) + (size_t)t * HH + ccol] = hn;
                __hip_bfloat16 hb16 = __float2bfloat16(hn);
                sSH[row][l15] = *(unsigned short*)&hb16;
                hprev[i] = hn;
            }
        }
        __syncthreads();
        if (tid < 128) {
            int row = tid >> 2, c4 = (tid & 3) << 2;
            u2v v = *reinterpret_cast<const u2v*>(&sSH[row][c4]);
            cstore8(hpub + (size_t)row * HH + bcol0 + c4, v);
        }
        asm volatile("s_waitcnt vmcnt(0)" ::: "memory");
        __syncthreads();
        if (tid == 0)
            __hip_atomic_store(&gflagB[b * 16], t + 1, __ATOMIC_RELAXED, __HIP_MEMORY_SCOPE_AGENT);
    }
}

// ---------------------------------------------------------------------------
extern "C" void kernel_launch(void* const* d_in, const int* in_sizes, int n_in,
                              void* d_out, int out_size, void* d_ws, size_t ws_size,
                              hipStream_t stream) {
    const float* X  = (const float*)d_in[0];
    const float* gk = (const float*)d_in[1];
    const float* gb = (const float*)d_in[2];
    const float* ck = (const float*)d_in[3];
    const float* cb = (const float*)d_in[4];
    float* out = (float*)d_out;
    char* ws = (char*)d_ws;
    if (ws_size < OFF_FLG + SZ_FLG) return;

    unsigned short* WgT  = (unsigned short*)(ws + OFF_WGT);
    unsigned short* WcT  = (unsigned short*)(ws + OFF_WCT);
    unsigned short* Xbf  = (unsigned short*)(ws + OFF_XBF);
    unsigned short* hpub = (unsigned short*)(ws + OFF_HPB);
    unsigned short* rpub = (unsigned short*)(ws + OFF_RPB);
    int*            gflagA = (int*)(ws + OFF_FLG);
    int*            gflagB = gflagA + NBLK * 16;

    hipMemsetAsync(gflagA, 0, SZ_FLG, stream);

    dim3 tb(256);
    wtr_kernel<<<dim3(2 * HH / 32, KK / 32), tb, 0, stream>>>(gk, WgT, 2 * HH);
    wtr_kernel<<<dim3(HH / 32, KK / 32), tb, 0, stream>>>(ck, WcT, HH);
    xconv_kernel<<<(BB * TT * DD) / (256 * 4), tb, 0, stream>>>(X, Xbf);

    gru_kernel<<<NBLK, dim3(TPB), 0, stream>>>(Xbf, WgT, WcT, gb, cb, out,
                                               hpub, rpub, gflagA, gflagB);
}

// Round 7
// 3914.046 us; speedup vs baseline: 3.4419x; 1.1603x over previous
//
#include <hip/hip_runtime.h>
#include <hip/hip_bf16.h>

typedef short s8v __attribute__((ext_vector_type(8)));
typedef float f4v __attribute__((ext_vector_type(4)));
typedef unsigned int u4v __attribute__((ext_vector_type(4)));
typedef unsigned int u2v __attribute__((ext_vector_type(2)));

#define NBLK 64
#define TPB 512

constexpr int BB = 32, TT = 512, DD = 512, HH = 1024;
constexpr int KK = DD + HH;          // 1536
constexpr int PK = KK + 8;           // padded LDS K-stride (16B-aligned rows)
constexpr int PK8 = PK / 8;
constexpr int K8 = KK / 8;

// ---- workspace layout (bytes) ----
constexpr size_t OFF_WGT = 0;
constexpr size_t SZ_WGT  = (size_t)2 * HH * KK * 2;
constexpr size_t OFF_WCT = OFF_WGT + SZ_WGT;
constexpr size_t SZ_WCT  = (size_t)HH * KK * 2;
constexpr size_t OFF_XBF = OFF_WCT + SZ_WCT;
constexpr size_t SZ_XBF  = (size_t)BB * TT * DD * 2;
constexpr size_t OFF_HPB = OFF_XBF + SZ_XBF;                    // h publish (coherent)
constexpr size_t SZ_PUB  = (size_t)BB * HH * 2;
constexpr size_t OFF_RPB = OFF_HPB + SZ_PUB;                    // rh publish (coherent)
constexpr size_t OFF_FLG = OFF_RPB + SZ_PUB;                    // 2 arrays x 64 blk x 2 waves x 16 ints
constexpr size_t SZ_FLG  = (size_t)2 * NBLK * 2 * 16 * 4;       // 16,384

// ---------------------------------------------------------------------------
__global__ void wtr_kernel(const float* __restrict__ in, unsigned short* __restrict__ out, int N) {
    __shared__ float tl[32][33];
    int tx = threadIdx.x & 31, ty = threadIdx.x >> 5;
    int n0 = blockIdx.x * 32, k0 = blockIdx.y * 32;
#pragma unroll
    for (int r = ty; r < 32; r += 8) tl[r][tx] = in[(size_t)(k0 + r) * N + n0 + tx];
    __syncthreads();
#pragma unroll
    for (int r = ty; r < 32; r += 8) {
        __hip_bfloat16 h = __float2bfloat16(tl[tx][r]);
        out[(size_t)(n0 + r) * KK + k0 + tx] = *reinterpret_cast<unsigned short*>(&h);
    }
}

__global__ void xconv_kernel(const float* __restrict__ X, unsigned short* __restrict__ Xbf) {
    size_t i = ((size_t)blockIdx.x * 256 + threadIdx.x) * 4;
    float4 v = *reinterpret_cast<const float4*>(X + i);
    __hip_bfloat16 h0 = __float2bfloat16(v.x), h1 = __float2bfloat16(v.y);
    __hip_bfloat16 h2 = __float2bfloat16(v.z), h3 = __float2bfloat16(v.w);
    ushort4 o;
    o.x = *(unsigned short*)&h0; o.y = *(unsigned short*)&h1;
    o.z = *(unsigned short*)&h2; o.w = *(unsigned short*)&h3;
    *reinterpret_cast<ushort4*>(Xbf + i) = o;
}

// ---------------------------------------------------------------------------
// Proven coherent primitives (r2-r6): agent-scope atomics for flags, sc0 sc1
// loads/stores for exchanged data. No fences, no other cache-scope tricks.
__device__ __forceinline__ u4v cload16(const void* p) {
    u4v r; asm volatile("global_load_dwordx4 %0, %1, off sc0 sc1" : "=v"(r) : "v"(p) : "memory"); return r;
}
__device__ __forceinline__ void cstore8(void* p, u2v v) {
    asm volatile("global_store_dwordx2 %0, %1, off sc0 sc1" :: "v"(p), "v"(v) : "memory");
}
#define B16(x) __builtin_bit_cast(s8v, (x))
#define WAIT_VM(n) do { asm volatile("s_waitcnt vmcnt(" #n ")" ::: "memory"); \
                        __builtin_amdgcn_sched_barrier(0); } while (0)

// Per-wave poll: lanes 0..15 poll the 16 producer-wave flags this wave's
// K-slice depends on. No block barrier; wave reconverges at the 'if' end.
__device__ __forceinline__ void poll16(const int* f, int blk0, int rtw, int gen, int lane) {
    if (lane < 16) {
        const int* fp = f + ((size_t)(blk0 + lane) * 2 + rtw) * 16;
        while (__hip_atomic_load(fp, __ATOMIC_RELAXED, __HIP_MEMORY_SCOPE_AGENT) < gen)
            __builtin_amdgcn_s_sleep(1);
    }
    asm volatile("" ::: "memory");     // keep subsequent coherent loads below the poll
}

#define MFMA(A, B, C) __builtin_amdgcn_mfma_f32_16x16x32_bf16((A), (B), (C), 0, 0, 0)

// ---------------------------------------------------------------------------
// Persistent kernel, 64 blocks x 512 threads (8 waves), 1 block/CU.
// Block b owns r/u/cand columns [b*16, b*16+16).
// Waves: ks = wid>>1 (4-way K-split), rt = wid&1 (batch-row tile of 16 rows).
// Finalizer waves (ks==0, i.e. tid<128) keep hprev+u in registers, finalize
// gates/candidate, and publish h/rh slices + their own per-wave flag.
__global__ __launch_bounds__(TPB, 1) void gru_kernel(
    const unsigned short* __restrict__ Xbf,
    const unsigned short* __restrict__ WgT,
    const unsigned short* __restrict__ WcT,
    const float* __restrict__ bg,
    const float* __restrict__ bc,
    float* __restrict__ out,
    unsigned short* __restrict__ hpub,
    unsigned short* __restrict__ rpub,
    int* __restrict__ gflagA,
    int* __restrict__ gflagB)
{
    __shared__ unsigned short sWg[32 * PK];   // 98,816 B
    __shared__ unsigned short sWc[16 * PK];   // 49,408 B
    __shared__ float sP[3][2][2][16][16];     // 12,288 B  [slot][rt][cg][row][col]
    __shared__ unsigned short sStage[32][16]; //  1,024 B  (bf16 transpose stage)
                                              // total 161,536 B

    const int b    = blockIdx.x;
    const int tid  = threadIdx.x;
    const int wid  = tid >> 6;
    const int lane = tid & 63;
    const int l15  = lane & 15;
    const int lq   = lane >> 4;
    const int ks   = wid >> 1;
    const int rt   = wid & 1;
    const int roff = rt * 16;
    const int arow = roff + l15;
    const int bcol0= b * 16;

    // ---- stage weight slices into LDS (once) ----
    {
        s8v* dst = (s8v*)sWg;
        for (int idx = tid; idx < 32 * K8; idx += TPB) {
            int c = idx / K8, k8 = idx % K8;
            int gc = (c < 16) ? (bcol0 + c) : (HH + bcol0 + (c - 16));
            dst[c * PK8 + k8] = ((const s8v*)(WgT + (size_t)gc * KK))[k8];
        }
        s8v* dst2 = (s8v*)sWc;
        for (int idx = tid; idx < 16 * K8; idx += TPB) {
            int c = idx / K8, k8 = idx % K8;
            dst2[c * PK8 + k8] = ((const s8v*)(WcT + (size_t)(bcol0 + c) * KK))[k8];
        }
    }

    const float bgr = bg[bcol0 + l15];        // r bias
    const float bgu = bg[HH + bcol0 + l15];   // u bias
    const float bcv = bc[bcol0 + l15];
    const int   ccol = bcol0 + l15;

    const s8v* sWg8 = (const s8v*)sWg;
    const s8v* sWc8 = (const s8v*)sWc;
    const s8v* bwr = sWg8 + l15 * PK8 + lq;          // r-col weights
    const s8v* bwu = sWg8 + (16 + l15) * PK8 + lq;   // u-col weights
    const s8v* bwc = sWc8 + l15 * PK8 + lq;          // cand weights
    const s8v* bwrx = bwr + 16 * ks;                 // x chunks [4ks..4ks+4)
    const s8v* bwux = bwu + 16 * ks;
    const s8v* bwrh = bwr + 64 + 32 * ks;            // h chunks [8ks..8ks+8)
    const s8v* bwuh = bwu + 64 + 32 * ks;
    const s8v* bwcx = bwc + 16 * ks;
    const s8v* bwch = bwc + 64 + 32 * ks;

    float hprev[4] = {0.f, 0.f, 0.f, 0.f};   // valid in ks==0 waves
    float ureg[4]  = {0.f, 0.f, 0.f, 0.f};

    __syncthreads();

#pragma unroll 1
    for (int t = 0; t < TT; ++t) {
        const s8v* xk = (const s8v*)(Xbf + (size_t)arow * (TT * DD) + (size_t)t * DD) + lq + 16 * ks;

        // ========== Phase A: gates (4-way K-split). x-part first ==========
        f4v ar0 = {0,0,0,0}, ar1 = {0,0,0,0}, au0 = {0,0,0,0}, au1 = {0,0,0,0};
        {
            s8v x0 = xk[0], x1 = xk[4], x2 = xk[8], x3 = xk[12];
            ar0 = MFMA(x0, bwrx[0],  ar0); au0 = MFMA(x0, bwux[0],  au0);
            ar1 = MFMA(x1, bwrx[4],  ar1); au1 = MFMA(x1, bwux[4],  au1);
            ar0 = MFMA(x2, bwrx[8],  ar0); au0 = MFMA(x2, bwux[8],  au0);
            ar1 = MFMA(x3, bwrx[12], ar1); au1 = MFMA(x3, bwux[12], au1);
        }

        if (t > 0) {
            poll16(gflagB, ks * 16, rt, t, lane);        // only my 16 producers
            const unsigned short* hp = hpub + (size_t)arow * HH + ks * 256 + lq * 8;
            u4v hb[8];
#pragma unroll
            for (int j = 0; j < 8; ++j) hb[j] = cload16(hp + (size_t)j * 32);
            WAIT_VM(4);
            ar0 = MFMA(B16(hb[0]), bwrh[0],  ar0); au0 = MFMA(B16(hb[0]), bwuh[0],  au0);
            ar1 = MFMA(B16(hb[1]), bwrh[4],  ar1); au1 = MFMA(B16(hb[1]), bwuh[4],  au1);
            ar0 = MFMA(B16(hb[2]), bwrh[8],  ar0); au0 = MFMA(B16(hb[2]), bwuh[8],  au0);
            ar1 = MFMA(B16(hb[3]), bwrh[12], ar1); au1 = MFMA(B16(hb[3]), bwuh[12], au1);
            WAIT_VM(0);
            ar0 = MFMA(B16(hb[4]), bwrh[16], ar0); au0 = MFMA(B16(hb[4]), bwuh[16], au0);
            ar1 = MFMA(B16(hb[5]), bwrh[20], ar1); au1 = MFMA(B16(hb[5]), bwuh[20], au1);
            ar0 = MFMA(B16(hb[6]), bwrh[24], ar0); au0 = MFMA(B16(hb[6]), bwuh[24], au0);
            ar1 = MFMA(B16(hb[7]), bwrh[28], ar1); au1 = MFMA(B16(hb[7]), bwuh[28], au1);
        }

        f4v pr = ar0 + ar1, pu = au0 + au1;
        if (ks > 0) {
#pragma unroll
            for (int i = 0; i < 4; ++i) {
                sP[ks - 1][rt][0][lq * 4 + i][l15] = pr[i];
                sP[ks - 1][rt][1][lq * 4 + i][l15] = pu[i];
            }
        }
        __syncthreads();                                 // S1: A partials ready
        float zr[4], zu[4];
        if (ks == 0) {
#pragma unroll
            for (int i = 0; i < 4; ++i) {
                int rr = lq * 4 + i;
                zr[i] = pr[i] + sP[0][rt][0][rr][l15] + sP[1][rt][0][rr][l15]
                              + sP[2][rt][0][rr][l15] + bgr;
                zu[i] = pu[i] + sP[0][rt][1][rr][l15] + sP[1][rt][1][rr][l15]
                              + sP[2][rt][1][rr][l15] + bgu;
            }
        }
        __syncthreads();                                 // S2: sP free for reuse
        if (ks == 0) {
#pragma unroll
            for (int i = 0; i < 4; ++i) {
                float r = 1.f / (1.f + __expf(-zr[i]));
                ureg[i] = 1.f / (1.f + __expf(-zu[i]));
                __hip_bfloat16 hb16 = __float2bfloat16(r * hprev[i]);
                sStage[roff + lq * 4 + i][l15] = *(unsigned short*)&hb16;
            }
            if (t > 0) {                                 // rh_0 == 0, never read
                int prow = roff + (lane >> 2), pc4 = (lane & 3) * 4;
                u2v v = *reinterpret_cast<const u2v*>(&sStage[prow][pc4]);  // same-wave LDS
                cstore8(rpub + (size_t)prow * HH + bcol0 + pc4, v);
                asm volatile("s_waitcnt vmcnt(0)" ::: "memory");
                if (lane == 0)
                    __hip_atomic_store(&gflagA[(b * 2 + rt) * 16], t,
                                       __ATOMIC_RELAXED, __HIP_MEMORY_SCOPE_AGENT);
            }
        }

        // ========== Phase B: candidate (4-way K-split). x-part first ==========
        f4v c0 = {0,0,0,0}, c1 = {0,0,0,0};
        {
            s8v x0 = xk[0], x1 = xk[4], x2 = xk[8], x3 = xk[12];
            c0 = MFMA(x0, bwcx[0],  c0); c1 = MFMA(x1, bwcx[4],  c1);
            c0 = MFMA(x2, bwcx[8],  c0); c1 = MFMA(x3, bwcx[12], c1);
        }

        if (t > 0) {
            poll16(gflagA, ks * 16, rt, t, lane);
            const unsigned short* rp = rpub + (size_t)arow * HH + ks * 256 + lq * 8;
            u4v rb[8];
#pragma unroll
            for (int j = 0; j < 8; ++j) rb[j] = cload16(rp + (size_t)j * 32);
            WAIT_VM(4);
            c0 = MFMA(B16(rb[0]), bwch[0],  c0); c1 = MFMA(B16(rb[1]), bwch[4],  c1);
            c0 = MFMA(B16(rb[2]), bwch[8],  c0); c1 = MFMA(B16(rb[3]), bwch[12], c1);
            WAIT_VM(0);
            c0 = MFMA(B16(rb[4]), bwch[16], c0); c1 = MFMA(B16(rb[5]), bwch[20], c1);
            c0 = MFMA(B16(rb[6]), bwch[24], c0); c1 = MFMA(B16(rb[7]), bwch[28], c1);
        }

        f4v pc = c0 + c1;
        if (ks > 0) {
#pragma unroll
            for (int i = 0; i < 4; ++i) sP[ks - 1][rt][0][lq * 4 + i][l15] = pc[i];
        }
        __syncthreads();                                 // S3: B partials ready
        float zc[4];
        if (ks == 0) {
#pragma unroll
            for (int i = 0; i < 4; ++i) {
                int rr = lq * 4 + i;
                zc[i] = pc[i] + sP[0][rt][0][rr][l15] + sP[1][rt][0][rr][l15]
                              + sP[2][rt][0][rr][l15] + bcv;
            }
        }
        __syncthreads();                                 // S4: sP free for next step
        if (ks == 0) {
#pragma unroll
            for (int i = 0; i < 4; ++i) {
                float e = __expf(2.f * zc[i]);
                float cv = 1.f - 2.f / (e + 1.f);
                float hn = ureg[i] * hprev[i] + (1.f - ureg[i]) * cv;
                hprev[i] = hn;
                __hip_bfloat16 hb16 = __float2bfloat16(hn);
                sStage[roff + lq * 4 + i][l15] = *(unsigned short*)&hb16;
            }
            int prow = roff + (lane >> 2), pc4 = (lane & 3) * 4;
            u2v v = *reinterpret_cast<const u2v*>(&sStage[prow][pc4]);      // same-wave LDS
            cstore8(hpub + (size_t)prow * HH + bcol0 + pc4, v);
            asm volatile("s_waitcnt vmcnt(0)" ::: "memory");
            if (lane == 0)
                __hip_atomic_store(&gflagB[(b * 2 + rt) * 16], t + 1,
                                   __ATOMIC_RELAXED, __HIP_MEMORY_SCOPE_AGENT);
            // out stores AFTER the flag — off the rendezvous critical path
#pragma unroll
            for (int i = 0; i < 4; ++i) {
                int row = roff + lq * 4 + i;
                out[(size_t)row * (TT * HH) + (size_t)t * HH + ccol] = hprev[i];
            }
        }
    }
}

// ---------------------------------------------------------------------------
extern "C" void kernel_launch(void* const* d_in, const int* in_sizes, int n_in,
                              void* d_out, int out_size, void* d_ws, size_t ws_size,
                              hipStream_t stream) {
    const float* X  = (const float*)d_in[0];
    const float* gk = (const float*)d_in[1];
    const float* gb = (const float*)d_in[2];
    const float* ck = (const float*)d_in[3];
    const float* cb = (const float*)d_in[4];
    float* out = (float*)d_out;
    char* ws = (char*)d_ws;
    if (ws_size < OFF_FLG + SZ_FLG) return;

    unsigned short* WgT  = (unsigned short*)(ws + OFF_WGT);
    unsigned short* WcT  = (unsigned short*)(ws + OFF_WCT);
    unsigned short* Xbf  = (unsigned short*)(ws + OFF_XBF);
    unsigned short* hpub = (unsigned short*)(ws + OFF_HPB);
    unsigned short* rpub = (unsigned short*)(ws + OFF_RPB);
    int*            gflagA = (int*)(ws + OFF_FLG);
    int*            gflagB = gflagA + NBLK * 2 * 16;

    hipMemsetAsync(gflagA, 0, SZ_FLG, stream);

    dim3 tb(256);
    wtr_kernel<<<dim3(2 * HH / 32, KK / 32), tb, 0, stream>>>(gk, WgT, 2 * HH);
    wtr_kernel<<<dim3(HH / 32, KK / 32), tb, 0, stream>>>(ck, WcT, HH);
    xconv_kernel<<<(BB * TT * DD) / (256 * 4), tb, 0, stream>>>(X, Xbf);

    gru_kernel<<<NBLK, dim3(TPB), 0, stream>>>(Xbf, WgT, WcT, gb, cb, out,
                                               hpub, rpub, gflagA, gflagB);
}